// Round 2
// baseline (6472.604 us; speedup 1.0000x reference)
//
#include <hip/hip_runtime.h>
#include <hip/hip_bf16.h>

// LSTM B=256 T=512 H=256 E=6 V=10 C=10. fp32 in/out (per reference jnp.float32).
// Internally: Wh and h rounded to bf16 for MFMA; x-path table, biases, c-state fp32.
// 16 column-groups x 16 row-blocks = 256 blocks x 256 threads (persistent, 1 block/CU).
// Weights live in registers as MFMA B-fragments; h exchanged via double-buffered
// global bf16 buffer + per-group monotone atomic barrier (agent scope).

typedef __attribute__((ext_vector_type(8))) short short8;
typedef __attribute__((ext_vector_type(4))) float f32x4;

#define HB_HALF 65536                                  // elems per h buffer (256 cols * 256 k)
#define FLAGS_BYTE_OFF (2 * HB_HALF * 2)               // 262144 B: after 2 bf16 h buffers

__device__ __forceinline__ float bf2f(__hip_bfloat16 v) { return __bfloat162float(v); }
__device__ __forceinline__ short f2bs(float v) {
    __hip_bfloat16 b = __float2bfloat16(v);
    return *(short*)&b;
}

__global__ __launch_bounds__(256) void lstm_persistent(
    const int* __restrict__ x,
    const float* __restrict__ emb,
    const float* __restrict__ Wxg, const float* __restrict__ Whg, const float* __restrict__ bg,
    const float* __restrict__ Wxi, const float* __restrict__ Whi, const float* __restrict__ bi,
    const float* __restrict__ Wxf, const float* __restrict__ Whf, const float* __restrict__ bff,
    const float* __restrict__ Wxo, const float* __restrict__ Who, const float* __restrict__ bo,
    const float* __restrict__ Wp, const float* __restrict__ bp,
    float* __restrict__ out,
    __hip_bfloat16* __restrict__ hb,        // [2][256 cols][256 k] bf16 (k = hidden row)
    unsigned int* __restrict__ flags)       // 16 groups * 16 uints (64B stride)
{
    const int tid  = threadIdx.x;
    const int bid  = blockIdx.x;
    const int g    = bid & 15;     // column group; peers {g, g+16, ...}: same bid%8 -> same XCD (heuristic)
    const int r    = bid >> 4;     // row block
    const int c0   = g * 16, r0 = r * 16;
    const int wave = tid >> 6, lane = tid & 63;
    const int lane_lo = lane & 15, quad = lane >> 4;

    __shared__ unsigned char xd[16][512];   // digits for this group's 16 cols
    __shared__ float tbl[4][16][10];        // gate x local-row x digit: Wx@emb table (exact fp32)
    __shared__ float biasv[4][16];          // gate x COLUMN (trailing-axis broadcast!)
    __shared__ float pre[4][16][17];        // gate x row x col (+1 pad)

    // ---- stage x digits for our columns ----
    for (int idx = tid; idx < 16 * 512; idx += 256) {
        int col = idx >> 9, t = idx & 511;
        xd[col][t] = (unsigned char)x[(c0 + col) * 512 + t];
    }
    // ---- Wx @ emb lookup tables for our 16 rows (fp32, exact) ----
    const float* WxT[4] = {Wxg, Wxi, Wxf, Wxo};
    const float* WhT[4] = {Whg, Whi, Whf, Who};
    const float* bT[4]  = {bg, bi, bff, bo};
    for (int idx = tid; idx < 640; idx += 256) {
        int gate = idx / 160, rem = idx % 160;
        int row = rem / 10, d = rem % 10;
        float s = 0.f;
        #pragma unroll
        for (int e = 0; e < 6; e++)
            s += WxT[gate][(r0 + row) * 6 + e] * emb[d * 6 + e];
        tbl[gate][row][d] = s;
    }
    if (tid < 64) {  // bias broadcasts over trailing (batch) axis: indexed by column
        int gate = tid >> 4, j = tid & 15;
        biasv[gate][j] = bT[gate][c0 + j];
    }

    // ---- preload this wave's gate-weight slice as bf16 MFMA B-fragments ----
    // B[k][n]: n = lane&15 -> hidden row r0+n ; k = kt*32 + quad*8 + j (row-major W)
    const float* W = WhT[wave];
    short8 wf[8];
    #pragma unroll
    for (int kt = 0; kt < 8; kt++) {
        const float* src = W + (r0 + lane_lo) * 256 + kt * 32 + quad * 8;
        short8 v;
        #pragma unroll
        for (int j = 0; j < 8; j++) v[j] = f2bs(src[j]);
        wf[kt] = v;
    }

    float c_state = 0.f;                    // this thread's c[r0+erow][c0+ecol]
    const int erow = tid & 15, ecol = tid >> 4;
    unsigned int* flag = flags + g * 16;

    __syncthreads();

    for (int t = 0; t < 512; t++) {
        f32x4 acc = {0.f, 0.f, 0.f, 0.f};
        if (t > 0) {
            // A[m][k] = h_{t-1}[k][c0+m]; lane: m=lane&15, k=quad*8+j (+32*kt), 16B loads
            const __hip_bfloat16* hsrc = hb + ((t - 1) & 1) * HB_HALF + (c0 + lane_lo) * 256 + quad * 8;
            #pragma unroll
            for (int kt = 0; kt < 8; kt++) {
                short8 af = *(const short8*)(const void*)(hsrc + kt * 32);
                acc = __builtin_amdgcn_mfma_f32_16x16x32_bf16(af, wf[kt], acc, 0, 0, 0);
            }
        }
        // D[m][n]: m=quad*4+i (our column index), n=lane&15 (our row index)
        #pragma unroll
        for (int i = 0; i < 4; i++)
            pre[wave][lane_lo][quad * 4 + i] = acc[i];
        __syncthreads();

        // ---- elementwise gate combine: thread owns (erow, ecol) ----
        {
            int d = xd[ecol][t];
            float pg = pre[0][erow][ecol] + tbl[0][erow][d] + biasv[0][ecol];
            float pi = pre[1][erow][ecol] + tbl[1][erow][d] + biasv[1][ecol];
            float pf = pre[2][erow][ecol] + tbl[2][erow][d] + biasv[2][ecol];
            float po = pre[3][erow][ecol] + tbl[3][erow][d] + biasv[3][ecol];
            float gg = 1.f - 2.f / (1.f + __expf(2.f * pg));   // tanh
            float ii = 1.f / (1.f + __expf(-pi));
            float ff = 1.f / (1.f + __expf(-pf));
            float oo = 1.f / (1.f + __expf(-po));
            c_state = gg * ii + c_state * ff;
            float hh = (1.f - 2.f / (1.f + __expf(2.f * c_state))) * oo;
            hb[(t & 1) * HB_HALF + (c0 + ecol) * 256 + (r0 + erow)] = __float2bfloat16(hh);
        }
        __syncthreads();  // all h stores issued; barrier implies vmcnt drain

        // ---- per-group barrier: monotone counter, release/acquire at agent scope ----
        if (tid == 0) {
            __threadfence();  // release: flush dirty L2 (cross-XCD visibility)
            __hip_atomic_fetch_add(flag, 1u, __ATOMIC_RELEASE, __HIP_MEMORY_SCOPE_AGENT);
            unsigned int target = 16u * (unsigned)(t + 1);
            while (__hip_atomic_load(flag, __ATOMIC_RELAXED, __HIP_MEMORY_SCOPE_AGENT) < target) { }
            __threadfence();  // acquire: invalidate stale lines before reading peers' slices
        }
        __syncthreads();
    }

    // ---- projection: out[b,cls] = Wp @ h_final + bp, by r==0 blocks ----
    if (r == 0 && tid < 160) {
        int col = tid / 10, cls = tid - col * 10;
        const __hip_bfloat16* hcol = hb + HB_HALF + (c0 + col) * 256;  // t=511 parity = 1
        const float* wrow = Wp + cls * 256;
        float s = 0.f;
        #pragma unroll 8
        for (int k = 0; k < 256; k++)
            s += bf2f(hcol[k]) * wrow[k];
        s += bp[cls];
        out[(c0 + col) * 10 + cls] = s;
    }
}

extern "C" void kernel_launch(void* const* d_in, const int* in_sizes, int n_in,
                              void* d_out, int out_size, void* d_ws, size_t ws_size,
                              hipStream_t stream) {
    const int*   x   = (const int*)d_in[0];
    const float* emb = (const float*)d_in[1];
    const float* Wxg = (const float*)d_in[2];
    const float* Whg = (const float*)d_in[3];
    const float* bg  = (const float*)d_in[4];
    const float* Wxi = (const float*)d_in[5];
    const float* Whi = (const float*)d_in[6];
    const float* bi  = (const float*)d_in[7];
    const float* Wxf = (const float*)d_in[8];
    const float* Whf = (const float*)d_in[9];
    const float* bff = (const float*)d_in[10];
    const float* Wxo = (const float*)d_in[11];
    const float* Who = (const float*)d_in[12];
    const float* bo  = (const float*)d_in[13];
    const float* Wp  = (const float*)d_in[14];
    const float* bp  = (const float*)d_in[15];

    __hip_bfloat16* hbuf  = (__hip_bfloat16*)d_ws;
    unsigned int*   flags = (unsigned int*)((char*)d_ws + FLAGS_BYTE_OFF);

    // barrier counters must start at 0 every call (ws is re-poisoned to 0xAA)
    hipMemsetAsync(flags, 0, 16 * 16 * sizeof(unsigned int), stream);

    hipLaunchKernelGGL(lstm_persistent, dim3(256), dim3(256), 0, stream,
                       x, emb, Wxg, Whg, bg, Wxi, Whi, bi, Wxf, Whf, bff,
                       Wxo, Who, bo, Wp, bp,
                       (float*)d_out, hbuf, flags);
}

// Round 3
// 2556.351 us; speedup vs baseline: 2.5320x; 2.5320x over previous
//
#include <hip/hip_runtime.h>
#include <hip/hip_bf16.h>

// LSTM B=256 T=512 H=256 E=6 V=10 C=10. fp32 in/out.
// 16 blocks (one per 16-column batch group) x 512 threads (8 waves).
// Recurrence is fully block-local: h lives in LDS, 2 syncthreads/step, NO
// cross-block fences/atomics. Weights (4 gates x 256x256 bf16 = 512 KB/block):
//   - 40 frags/wave in VGPRs (g,i + f.kt0-3)
//   - 10 frags/wave in LDS (f.kt4-7 + o.kt0)          = 80 KB
//   - 14 frags/wave streamed per step from block-private bf16 copy in d_ws
// x-path folded into a [row][digit] bf16 table (Wx @ emb), built once.

typedef __attribute__((ext_vector_type(8))) short short8;
typedef __attribute__((ext_vector_type(4))) float f32x4;

#define MFMA(a, b, c) __builtin_amdgcn_mfma_f32_16x16x32_bf16(a, b, c, 0, 0, 0)

#define WS_PER_BLOCK (8 * 14 * 64 * 16)   // 114688 B: 8 waves x 14 slots x 64 lanes x 16 B

__device__ __forceinline__ float b2f(short s) {
    union { unsigned int u; float f; } v; v.u = ((unsigned int)(unsigned short)s) << 16; return v.f;
}
__device__ __forceinline__ short f2b(float f) {
    __hip_bfloat16 b = __float2bfloat16(f); return *(short*)&b;
}
__device__ __forceinline__ short8 cvt8(const float* p) {
    short8 r;
    #pragma unroll
    for (int j = 0; j < 8; j++) r[j] = f2b(p[j]);
    return r;
}
__device__ __forceinline__ float sigm(float v) { return 1.f / (1.f + __expf(-v)); }
__device__ __forceinline__ float tanh_(float v) { return 1.f - 2.f / (1.f + __expf(2.f * v)); }

__global__ __launch_bounds__(512, 2) void lstm_block(
    const int* __restrict__ x,
    const float* __restrict__ emb,
    const float* __restrict__ Wxg, const float* __restrict__ Whg, const float* __restrict__ bg,
    const float* __restrict__ Wxi, const float* __restrict__ Whi, const float* __restrict__ bi,
    const float* __restrict__ Wxf, const float* __restrict__ Whf, const float* __restrict__ bff,
    const float* __restrict__ Wxo, const float* __restrict__ Who, const float* __restrict__ bo,
    const float* __restrict__ Wp, const float* __restrict__ bp,
    float* __restrict__ out, short* __restrict__ ws)
{
    const int tid = threadIdx.x, bid = blockIdx.x;
    const int c0 = bid * 16;               // batch columns c0..c0+15
    const int w = tid >> 6, lane = tid & 63;
    const int l = lane & 15, q = lane >> 4;

    __shared__ short hlds[16 * 264];               // [col][k row], +8 pad: 2-way banks, 16B align
    __shared__ unsigned char xdig[16][512];        // digits for our columns
    __shared__ unsigned short tbl3[128 * 10 * 8];  // [p=16w+l][digit][g0..g3@rt0, g0..g3@rt1] bf16
    __shared__ float biaslds[16][4];               // [col][gate]  (trailing-axis broadcast)
    __shared__ short wlds[8 * 10 * 64 * 8];        // per-wave 10 LDS-resident frags

    const float* WxT[4] = {Wxg, Wxi, Wxf, Wxo};
    const float* WhT[4] = {Whg, Whi, Whf, Who};
    const float* bT[4]  = {bg, bi, bff, bo};

    // ---- init: zero h, stage digits ----
    for (int i = tid; i < 16 * 264; i += 512) hlds[i] = 0;
    for (int i = tid; i < 16 * 512; i += 512) {
        int col = i >> 9, t = i & 511;
        xdig[col][t] = (unsigned char)x[(c0 + col) * 512 + t];
    }
    // ---- x-path table: tbl3[p][d] = {g..o @ row 32w+l, g..o @ row 32w+16+l} ----
    for (int i = tid; i < 1280; i += 512) {
        int p = i / 10, d = i % 10;
        int rA = 32 * (p >> 4) + (p & 15), rB = rA + 16;
        #pragma unroll
        for (int g = 0; g < 4; g++) {
            float sA = 0.f, sB = 0.f;
            #pragma unroll
            for (int e = 0; e < 6; e++) {
                float em = emb[d * 6 + e];
                sA += WxT[g][rA * 6 + e] * em;
                sB += WxT[g][rB * 6 + e] * em;
            }
            tbl3[(p * 10 + d) * 8 + g]     = (unsigned short)f2b(sA);
            tbl3[(p * 10 + d) * 8 + 4 + g] = (unsigned short)f2b(sB);
        }
    }
    if (tid < 64) biaslds[tid >> 2][tid & 3] = bT[tid & 3][c0 + (tid >> 2)];

    // ---- weight fragments. B[k][n]: n=l -> W row, k=q*8+j ----
    // regs (40): g0,g1 all (rt*8+kt), g2 kt0-3 (32+rt*4+kt)
    short8 wreg[40];
    #pragma unroll
    for (int g = 0; g < 2; g++)
        #pragma unroll
        for (int rt = 0; rt < 2; rt++)
            #pragma unroll
            for (int kt = 0; kt < 8; kt++)
                wreg[g * 16 + rt * 8 + kt] = cvt8(WhT[g] + (32 * w + 16 * rt + l) * 256 + kt * 32 + q * 8);
    #pragma unroll
    for (int rt = 0; rt < 2; rt++)
        #pragma unroll
        for (int kt = 0; kt < 4; kt++)
            wreg[32 + rt * 4 + kt] = cvt8(Whf + (32 * w + 16 * rt + l) * 256 + kt * 32 + q * 8);
    // LDS (10/wave): g2 kt4-7 (lidx=rt*4+kt-4), g3 kt0 (lidx=8+rt)
    #pragma unroll
    for (int rt = 0; rt < 2; rt++)
        #pragma unroll
        for (int kt = 4; kt < 8; kt++)
            *(short8*)&wlds[((w * 10 + rt * 4 + kt - 4) * 64 + lane) * 8] =
                cvt8(Whf + (32 * w + 16 * rt + l) * 256 + kt * 32 + q * 8);
    #pragma unroll
    for (int rt = 0; rt < 2; rt++)
        *(short8*)&wlds[((w * 10 + 8 + rt) * 64 + lane) * 8] =
            cvt8(Who + (32 * w + 16 * rt + l) * 256 + q * 8);
    // stream copy (14/wave): g3 kt1-7, slot=(kt-1)*2+rt, block-private region of ws
    short8* wsb = (short8*)(ws + (size_t)bid * (WS_PER_BLOCK / 2));
    #pragma unroll
    for (int kt = 1; kt < 8; kt++)
        #pragma unroll
        for (int rt = 0; rt < 2; rt++)
            wsb[(w * 14 + (kt - 1) * 2 + rt) * 64 + lane] =
                cvt8(Who + (32 * w + 16 * rt + l) * 256 + kt * 32 + q * 8);

    float cs[2][4] = {{0.f, 0.f, 0.f, 0.f}, {0.f, 0.f, 0.f, 0.f}};
    const int aoff = l * 264 + q * 8;       // A-frag base in hlds (shorts)
    const short8* wlp = (const short8*)&wlds[(w * 10) * 64 * 8];
    const short8* wsp = wsb + w * 14 * 64;

    __syncthreads();

    for (int t = 0; t < 512; t++) {
        f32x4 acc[4][2];
        #pragma unroll
        for (int g = 0; g < 4; g++)
            #pragma unroll
            for (int rt = 0; rt < 2; rt++)
                acc[g][rt] = (f32x4){0.f, 0.f, 0.f, 0.f};

        // prefetch stream slots 0..5 (consumed at kt=1..3), ring of 6
        short8 sb0 = wsp[0 * 64 + lane], sb1 = wsp[1 * 64 + lane];
        short8 sb2 = wsp[2 * 64 + lane], sb3 = wsp[3 * 64 + lane];
        short8 sb4 = wsp[4 * 64 + lane], sb5 = wsp[5 * 64 + lane];

        #pragma unroll
        for (int kt = 0; kt < 8; kt++) {
            short8 af = *(const short8*)&hlds[aoff + kt * 32];
            #pragma unroll
            for (int rt = 0; rt < 2; rt++) {
                acc[0][rt] = MFMA(af, wreg[rt * 8 + kt], acc[0][rt]);
                acc[1][rt] = MFMA(af, wreg[16 + rt * 8 + kt], acc[1][rt]);
                acc[2][rt] = (kt < 4) ? MFMA(af, wreg[32 + rt * 4 + kt], acc[2][rt])
                                      : MFMA(af, wlp[(rt * 4 + kt - 4) * 64 + lane], acc[2][rt]);
            }
            if (kt == 0) {
                acc[3][0] = MFMA(af, wlp[8 * 64 + lane], acc[3][0]);
                acc[3][1] = MFMA(af, wlp[9 * 64 + lane], acc[3][1]);
            } else if (kt == 1) {
                acc[3][0] = MFMA(af, sb0, acc[3][0]); acc[3][1] = MFMA(af, sb1, acc[3][1]);
                sb0 = wsp[6 * 64 + lane]; sb1 = wsp[7 * 64 + lane];
            } else if (kt == 2) {
                acc[3][0] = MFMA(af, sb2, acc[3][0]); acc[3][1] = MFMA(af, sb3, acc[3][1]);
                sb2 = wsp[8 * 64 + lane]; sb3 = wsp[9 * 64 + lane];
            } else if (kt == 3) {
                acc[3][0] = MFMA(af, sb4, acc[3][0]); acc[3][1] = MFMA(af, sb5, acc[3][1]);
                sb4 = wsp[10 * 64 + lane]; sb5 = wsp[11 * 64 + lane];
            } else if (kt == 4) {
                acc[3][0] = MFMA(af, sb0, acc[3][0]); acc[3][1] = MFMA(af, sb1, acc[3][1]);
                sb0 = wsp[12 * 64 + lane]; sb1 = wsp[13 * 64 + lane];
            } else if (kt == 5) {
                acc[3][0] = MFMA(af, sb2, acc[3][0]); acc[3][1] = MFMA(af, sb3, acc[3][1]);
            } else if (kt == 6) {
                acc[3][0] = MFMA(af, sb4, acc[3][0]); acc[3][1] = MFMA(af, sb5, acc[3][1]);
            } else {
                acc[3][0] = MFMA(af, sb0, acc[3][0]); acc[3][1] = MFMA(af, sb1, acc[3][1]);
            }
        }
        __syncthreads();   // all A-reads of h_{t-1} complete block-wide

        // ---- elementwise: lane owns rows {32w+l, 32w+16+l}, cols q*4..q*4+3 ----
        #pragma unroll
        for (int i = 0; i < 4; i++) {
            int col = q * 4 + i;
            int d = xdig[col][t];
            short8 tb = *(const short8*)&tbl3[((w * 16 + l) * 10 + d) * 8];
            const float* bs = &biaslds[col][0];
            #pragma unroll
            for (int rt = 0; rt < 2; rt++) {
                float pg = acc[0][rt][i] + b2f(tb[rt * 4 + 0]) + bs[0];
                float pi = acc[1][rt][i] + b2f(tb[rt * 4 + 1]) + bs[1];
                float pf = acc[2][rt][i] + b2f(tb[rt * 4 + 2]) + bs[2];
                float po = acc[3][rt][i] + b2f(tb[rt * 4 + 3]) + bs[3];
                float c = tanh_(pg) * sigm(pi) + cs[rt][i] * sigm(pf);
                cs[rt][i] = c;
                float hh = tanh_(c) * sigm(po);
                hlds[col * 264 + 32 * w + 16 * rt + l] = f2b(hh);
            }
        }
        __syncthreads();   // h_t fully written before next step's reads
    }

    // ---- projection: out[c0+col][cls] = Wp[cls] . h_final + bp[cls] ----
    if (tid < 160) {
        int col = tid / 10, cls = tid - col * 10;
        const short* hcol = &hlds[col * 264];
        const float* wrow = Wp + cls * 256;
        float s = 0.f;
        #pragma unroll 8
        for (int k = 0; k < 256; k++) s += b2f(hcol[k]) * wrow[k];
        out[(c0 + col) * 10 + cls] = s + bp[cls];
    }
}

extern "C" void kernel_launch(void* const* d_in, const int* in_sizes, int n_in,
                              void* d_out, int out_size, void* d_ws, size_t ws_size,
                              hipStream_t stream) {
    const int*   x   = (const int*)d_in[0];
    const float* emb = (const float*)d_in[1];
    const float* Wxg = (const float*)d_in[2];
    const float* Whg = (const float*)d_in[3];
    const float* bg  = (const float*)d_in[4];
    const float* Wxi = (const float*)d_in[5];
    const float* Whi = (const float*)d_in[6];
    const float* bi  = (const float*)d_in[7];
    const float* Wxf = (const float*)d_in[8];
    const float* Whf = (const float*)d_in[9];
    const float* bff = (const float*)d_in[10];
    const float* Wxo = (const float*)d_in[11];
    const float* Who = (const float*)d_in[12];
    const float* bo  = (const float*)d_in[13];
    const float* Wp  = (const float*)d_in[14];
    const float* bp  = (const float*)d_in[15];

    hipLaunchKernelGGL(lstm_block, dim3(16), dim3(512), 0, stream,
                       x, emb, Wxg, Whg, bg, Wxi, Whi, bi, Wxf, Whf, bff,
                       Wxo, Who, bo, Wp, bp,
                       (float*)d_out, (short*)d_ws);
}

// Round 4
// 2436.403 us; speedup vs baseline: 2.6566x; 1.0492x over previous
//
#include <hip/hip_runtime.h>
#include <hip/hip_bf16.h>

// LSTM B=256 T=512 H=256 E=6 V=10 C=10. fp32 in/out.
// 16 blocks x 512 threads (8 waves, 2/SIMD). Block owns 16 batch cols; wave w
// owns hidden rows 32w..32w+31 for ALL 4 gates (8 M-tiles x 9 K-tiles).
// K-tile 8 folds x-path (one-hot digit @ k'=0..9) AND biases (indicator @
// k'=10..13) into the MFMA. Weight residency per wave: 36 frags regs,
// 17 frags LDS, 11 frags streamed from block-private L2 copy (4-slot ring,
// prefetch distance >= 3 k-tiles).

typedef __attribute__((ext_vector_type(8))) short short8;
typedef __attribute__((ext_vector_type(4))) float f32x4;

#define MFMA(a, b, c) __builtin_amdgcn_mfma_f32_16x16x32_bf16(a, b, c, 0, 0, 0)
#define WS_PER_BLOCK_BYTES (8 * 11 * 64 * 16)   // 90112: 8 waves x 11 frags x 1KB

__device__ __forceinline__ float b2f(short s) {
    union { unsigned int u; float f; } v; v.u = ((unsigned int)(unsigned short)s) << 16; return v.f;
}
__device__ __forceinline__ short f2b(float f) {
    __hip_bfloat16 b = __float2bfloat16(f); return *(short*)&b;
}
__device__ __forceinline__ short8 cvt8(const float* p) {
    short8 r;
    #pragma unroll
    for (int j = 0; j < 8; j++) r[j] = f2b(p[j]);
    return r;
}
__device__ __forceinline__ float sigm(float v) { return 1.f / (1.f + __expf(-v)); }
__device__ __forceinline__ float tanh_(float v) { return 1.f - 2.f / (1.f + __expf(2.f * v)); }

__global__ __launch_bounds__(512, 2) void lstm_block(
    const int* __restrict__ x,
    const float* __restrict__ emb,
    const float* __restrict__ Wxg, const float* __restrict__ Whg, const float* __restrict__ bg,
    const float* __restrict__ Wxi, const float* __restrict__ Whi, const float* __restrict__ bi,
    const float* __restrict__ Wxf, const float* __restrict__ Whf, const float* __restrict__ bff,
    const float* __restrict__ Wxo, const float* __restrict__ Who, const float* __restrict__ bo,
    const float* __restrict__ Wp, const float* __restrict__ bp,
    float* __restrict__ out, short* __restrict__ ws)
{
    const int tid = threadIdx.x, bid = blockIdx.x;
    const int c0 = bid * 16;
    const int w = tid >> 6, lane = tid & 63;
    const int l = lane & 15, q = lane >> 4;
    const int rw = 32 * w;                  // this wave's hidden-row base

    __shared__ __align__(16) short hlds[16 * 264];          // [col][k row] bf16, stride 264
    __shared__ __align__(16) short wlds[8 * 17 * 512];      // 17 LDS frags / wave (136 KB)
    __shared__ unsigned char xdig[16][512];
    __shared__ __align__(16) short onehotpat[96];           // [d][8]: one-hot j==d for d<8, else 0

    const float* WxT[4] = {Wxg, Wxi, Wxf, Wxo};
    const float* bT[4]  = {bg, bi, bff, bo};

    for (int i = tid; i < 16 * 264; i += 512) hlds[i] = 0;
    for (int i = tid; i < 16 * 512; i += 512) {
        int col = i >> 9, t = i & 511;
        xdig[col][t] = (unsigned char)x[(c0 + col) * 512 + t];
    }
    if (tid < 96) onehotpat[tid] = ((tid >> 3) < 8 && (tid & 7) == (tid >> 3)) ? (short)0x3F80 : (short)0;

    // ---- register frags: g0 (Whg), g1 (Whi) all kt; g2 (Whf) rt0 kt0-3 ----
    short8 wg0[2][8], wg1[2][8], wg2a[4];
    #pragma unroll
    for (int rt = 0; rt < 2; rt++)
        #pragma unroll
        for (int kt = 0; kt < 8; kt++) {
            wg0[rt][kt] = cvt8(Whg + (rw + 16 * rt + l) * 256 + kt * 32 + q * 8);
            wg1[rt][kt] = cvt8(Whi + (rw + 16 * rt + l) * 256 + kt * 32 + q * 8);
        }
    #pragma unroll
    for (int kt = 0; kt < 4; kt++)
        wg2a[kt] = cvt8(Whf + (rw + l) * 256 + kt * 32 + q * 8);

    // ---- LDS frags: idx 0-3 g2rt0 kt4-7; 4-11 g2rt1 kt0-7; 12-16 g3rt0 kt0-4 ----
    #pragma unroll
    for (int kt = 4; kt < 8; kt++)
        *(short8*)&wlds[((w * 17 + (kt - 4)) * 64 + lane) * 8] = cvt8(Whf + (rw + l) * 256 + kt * 32 + q * 8);
    #pragma unroll
    for (int kt = 0; kt < 8; kt++)
        *(short8*)&wlds[((w * 17 + 4 + kt) * 64 + lane) * 8] = cvt8(Whf + (rw + 16 + l) * 256 + kt * 32 + q * 8);
    #pragma unroll
    for (int kt = 0; kt < 5; kt++)
        *(short8*)&wlds[((w * 17 + 12 + kt) * 64 + lane) * 8] = cvt8(Who + (rw + l) * 256 + kt * 32 + q * 8);

    // ---- stream copy (11/wave): f0-7 g3rt1 kt0-7; f8-10 g3rt0 kt5-7 ----
    short8* wsb = (short8*)(ws + (size_t)bid * (WS_PER_BLOCK_BYTES / 2));
    short8* wsp = wsb + (w * 11) * 64;
    #pragma unroll
    for (int kt = 0; kt < 8; kt++)
        wsp[kt * 64 + lane] = cvt8(Who + (rw + 16 + l) * 256 + kt * 32 + q * 8);
    #pragma unroll
    for (int kt = 5; kt < 8; kt++)
        wsp[(kt + 3) * 64 + lane] = cvt8(Who + (rw + l) * 256 + kt * 32 + q * 8);

    // ---- fold frags (kt=8): oh[g][rt]: k'=0..9 -> T[g][row][d]; k'=10..13 -> gate indicator ----
    short8 oh[4][2];
    #pragma unroll
    for (int g = 0; g < 4; g++)
        #pragma unroll
        for (int rt = 0; rt < 2; rt++) {
            int row = rw + 16 * rt + l;
            short8 v = {0, 0, 0, 0, 0, 0, 0, 0};
            if (q == 0) {
                #pragma unroll
                for (int jj = 0; jj < 8; jj++) {
                    float s = 0.f;
                    #pragma unroll
                    for (int e = 0; e < 6; e++) s += WxT[g][row * 6 + e] * emb[jj * 6 + e];
                    v[jj] = f2b(s);
                }
            } else if (q == 1) {
                #pragma unroll
                for (int jj = 0; jj < 2; jj++) {
                    float s = 0.f;
                    #pragma unroll
                    for (int e = 0; e < 6; e++) s += WxT[g][row * 6 + e] * emb[(8 + jj) * 6 + e];
                    v[jj] = f2b(s);
                }
                v[2 + g] = (short)0x3F80;   // bias indicator: A carries bias_g at k'=10+g
            }
            oh[g][rt] = v;
        }

    // ---- A kt=8 q==1 base: j2..5 = bias_g[col l] (bf16) ----
    short8 af_base = {0, 0, 0, 0, 0, 0, 0, 0};
    af_base[2] = f2b(bg[c0 + l]);  af_base[3] = f2b(bi[c0 + l]);
    af_base[4] = f2b(bff[c0 + l]); af_base[5] = f2b(bo[c0 + l]);

    float cs[2][4] = {{0.f, 0.f, 0.f, 0.f}, {0.f, 0.f, 0.f, 0.f}};
    const int aoff = l * 264 + q * 8;
    #define LDSF(idx) (*(const short8*)&wlds[((w * 17 + (idx)) * 64 + lane) * 8])

    __syncthreads();

    // ring preload: next-consumed stream frags r1k0..r1k3
    short8 s0 = wsp[0 * 64 + lane], s1 = wsp[1 * 64 + lane];
    short8 s2 = wsp[2 * 64 + lane], s3 = wsp[3 * 64 + lane];

    for (int t = 0; t < 512; t++) {
        f32x4 acc[4][2];
        #pragma unroll
        for (int g = 0; g < 4; g++)
            #pragma unroll
            for (int rt = 0; rt < 2; rt++)
                acc[g][rt] = (f32x4){0.f, 0.f, 0.f, 0.f};

        #pragma unroll
        for (int kt = 0; kt < 8; kt++) {
            short8 af = *(const short8*)&hlds[aoff + kt * 32];
            acc[0][0] = MFMA(af, wg0[0][kt], acc[0][0]);
            acc[0][1] = MFMA(af, wg0[1][kt], acc[0][1]);
            acc[1][0] = MFMA(af, wg1[0][kt], acc[1][0]);
            acc[1][1] = MFMA(af, wg1[1][kt], acc[1][1]);
            acc[2][0] = (kt < 4) ? MFMA(af, wg2a[kt], acc[2][0]) : MFMA(af, LDSF(kt - 4), acc[2][0]);
            acc[2][1] = MFMA(af, LDSF(4 + kt), acc[2][1]);
            // g3: rt0 kt0-4 LDS, rest from stream ring (refill >=3 kt ahead)
            if (kt == 0) {
                acc[3][0] = MFMA(af, LDSF(12), acc[3][0]);
                acc[3][1] = MFMA(af, s0, acc[3][1]); s0 = wsp[4 * 64 + lane];   // r1k4
            } else if (kt == 1) {
                acc[3][0] = MFMA(af, LDSF(13), acc[3][0]);
                acc[3][1] = MFMA(af, s1, acc[3][1]); s1 = wsp[8 * 64 + lane];   // r0k5
            } else if (kt == 2) {
                acc[3][0] = MFMA(af, LDSF(14), acc[3][0]);
                acc[3][1] = MFMA(af, s2, acc[3][1]); s2 = wsp[5 * 64 + lane];   // r1k5
            } else if (kt == 3) {
                acc[3][0] = MFMA(af, LDSF(15), acc[3][0]);
                acc[3][1] = MFMA(af, s3, acc[3][1]); s3 = wsp[9 * 64 + lane];   // r0k6
            } else if (kt == 4) {
                acc[3][0] = MFMA(af, LDSF(16), acc[3][0]);
                acc[3][1] = MFMA(af, s0, acc[3][1]); s0 = wsp[6 * 64 + lane];   // r1k6
            } else if (kt == 5) {
                acc[3][0] = MFMA(af, s1, acc[3][0]);
                acc[3][1] = MFMA(af, s2, acc[3][1]);
                s1 = wsp[10 * 64 + lane];                                        // r0k7
                s2 = wsp[7 * 64 + lane];                                         // r1k7
            } else if (kt == 6) {
                acc[3][0] = MFMA(af, s3, acc[3][0]);
                acc[3][1] = MFMA(af, s0, acc[3][1]);
            } else {
                acc[3][0] = MFMA(af, s1, acc[3][0]);
                acc[3][1] = MFMA(af, s2, acc[3][1]);
            }
        }

        // ---- kt=8: folded x-path + bias ----
        {
            int d = xdig[l][t];
            short8 pd = *(const short8*)&onehotpat[d * 8];
            short8 bi8 = af_base;
            bi8[0] = (d == 8) ? (short)0x3F80 : (short)0;
            bi8[1] = (d == 9) ? (short)0x3F80 : (short)0;
            short8 z = {0, 0, 0, 0, 0, 0, 0, 0};
            short8 af8 = (q == 0) ? pd : ((q == 1) ? bi8 : z);
            #pragma unroll
            for (int g = 0; g < 4; g++) {
                acc[g][0] = MFMA(af8, oh[g][0], acc[g][0]);
                acc[g][1] = MFMA(af8, oh[g][1], acc[g][1]);
            }
        }
        __syncthreads();   // all hlds A-reads of h_{t-1} complete

        // ring preload for next step (distance: elementwise + barrier)
        s0 = wsp[0 * 64 + lane]; s1 = wsp[1 * 64 + lane];
        s2 = wsp[2 * 64 + lane]; s3 = wsp[3 * 64 + lane];

        // ---- elementwise: pure gates (x-path & bias already in acc) ----
        #pragma unroll
        for (int i = 0; i < 4; i++) {
            int col = q * 4 + i;
            #pragma unroll
            for (int rt = 0; rt < 2; rt++) {
                float c = tanh_(acc[0][rt][i]) * sigm(acc[1][rt][i]) + cs[rt][i] * sigm(acc[2][rt][i]);
                cs[rt][i] = c;
                float hh = tanh_(c) * sigm(acc[3][rt][i]);
                hlds[col * 264 + rw + 16 * rt + l] = f2b(hh);
            }
        }
        __syncthreads();   // h_t fully written
    }

    // ---- projection ----
    if (tid < 160) {
        int col = tid / 10, cls = tid - col * 10;
        const short* hcol = &hlds[col * 264];
        const float* wrow = Wp + cls * 256;
        float s = 0.f;
        #pragma unroll 8
        for (int k = 0; k < 256; k++) s += b2f(hcol[k]) * wrow[k];
        out[(c0 + col) * 10 + cls] = s + bp[cls];
    }
    #undef LDSF
}

extern "C" void kernel_launch(void* const* d_in, const int* in_sizes, int n_in,
                              void* d_out, int out_size, void* d_ws, size_t ws_size,
                              hipStream_t stream) {
    const int*   x   = (const int*)d_in[0];
    const float* emb = (const float*)d_in[1];
    const float* Wxg = (const float*)d_in[2];
    const float* Whg = (const float*)d_in[3];
    const float* bg  = (const float*)d_in[4];
    const float* Wxi = (const float*)d_in[5];
    const float* Whi = (const float*)d_in[6];
    const float* bi  = (const float*)d_in[7];
    const float* Wxf = (const float*)d_in[8];
    const float* Whf = (const float*)d_in[9];
    const float* bff = (const float*)d_in[10];
    const float* Wxo = (const float*)d_in[11];
    const float* Who = (const float*)d_in[12];
    const float* bo  = (const float*)d_in[13];
    const float* Wp  = (const float*)d_in[14];
    const float* bp  = (const float*)d_in[15];

    hipLaunchKernelGGL(lstm_block, dim3(16), dim3(512), 0, stream,
                       x, emb, Wxg, Whg, bg, Wxi, Whi, bi, Wxf, Whf, bff,
                       Wxo, Who, bo, Wp, bp,
                       (float*)d_out, (short*)d_ws);
}

// Round 5
// 1866.942 us; speedup vs baseline: 3.4670x; 1.3050x over previous
//
#include <hip/hip_runtime.h>
#include <hip/hip_bf16.h>

// LSTM B=256 T=512 H=256 E=6 V=10 C=10. fp32 in/out.
// 16 blocks x 512 threads (8 waves, exactly 2/SIMD -> amdgpu_waves_per_eu(2,2)
// unlocks 256 VGPR/wave). Block owns 16 batch cols; wave w owns hidden rows
// 32w..32w+31 for all 4 gates (8 M-tiles x 9 K-tiles; K-tile 8 folds x-path +
// biases into MFMA). Weight residency per wave (64 hot frags + 8 fold frags):
//   regs   32: g (Whg) + i (Whi), all rt/kt                (128 V)
//   LDS    17: f (Whf) all 16 + o (Who) rt0 kt0            (136 KB)
//   stream 15: o-gate rest, from block-private L2 copy:
//     early 7 (consumed kt0-3) loaded during prev elementwise phase,
//     late  8 (consumed kt4-7) loaded at kt0-3 same step (>=4kt distance).
// Elementwise uses v_rcp_f32 (__builtin_amdgcn_rcpf) to avoid div expansion.

typedef __attribute__((ext_vector_type(8))) short short8;
typedef __attribute__((ext_vector_type(4))) float f32x4;
typedef __attribute__((ext_vector_type(4))) float float4v;

#define MFMA(a, b, c) __builtin_amdgcn_mfma_f32_16x16x32_bf16(a, b, c, 0, 0, 0)
#define WS_STRIDE_SHORTS (8 * 15 * 64 * 8)   // per-block stream region: 8 waves x 15 frags x 1KB

__device__ __forceinline__ float b2f(short s) {
    union { unsigned int u; float f; } v; v.u = ((unsigned int)(unsigned short)s) << 16; return v.f;
}
__device__ __forceinline__ short f2b(float f) {
    __hip_bfloat16 b = __float2bfloat16(f); return *(short*)&b;
}
__device__ __forceinline__ short8 cvt8(const float* p) {
    float4v a = *(const float4v*)p, b = *(const float4v*)(p + 4);
    short8 r;
    r[0] = f2b(a[0]); r[1] = f2b(a[1]); r[2] = f2b(a[2]); r[3] = f2b(a[3]);
    r[4] = f2b(b[0]); r[5] = f2b(b[1]); r[6] = f2b(b[2]); r[7] = f2b(b[3]);
    return r;
}
__device__ __forceinline__ float sigm(float v) {
    return __builtin_amdgcn_rcpf(1.f + __expf(-v));
}
__device__ __forceinline__ float tanh_(float v) {
    return 1.f - 2.f * __builtin_amdgcn_rcpf(1.f + __expf(2.f * v));
}

__global__ __attribute__((amdgpu_flat_work_group_size(512, 512), amdgpu_waves_per_eu(2, 2)))
void lstm_block(
    const int* __restrict__ x,
    const float* __restrict__ emb,
    const float* __restrict__ Wxg, const float* __restrict__ Whg, const float* __restrict__ bg,
    const float* __restrict__ Wxi, const float* __restrict__ Whi, const float* __restrict__ bi,
    const float* __restrict__ Wxf, const float* __restrict__ Whf, const float* __restrict__ bff,
    const float* __restrict__ Wxo, const float* __restrict__ Who, const float* __restrict__ bo,
    const float* __restrict__ Wp, const float* __restrict__ bp,
    float* __restrict__ out, short* __restrict__ ws)
{
    const int tid = threadIdx.x, bid = blockIdx.x;
    const int c0 = bid * 16;
    const int w = tid >> 6, lane = tid & 63;
    const int l = lane & 15, q = lane >> 4;
    const int rw = 32 * w;

    __shared__ __align__(16) short hlds[16 * 264];       // [col][k row] bf16
    __shared__ __align__(16) short wlds[8 * 17 * 512];   // 17 LDS frags/wave
    __shared__ unsigned char xdig[16][512];
    __shared__ __align__(16) short onehotpat[96];

    const float* WxT[4] = {Wxg, Wxi, Wxf, Wxo};

    for (int i = tid; i < 16 * 264; i += 512) hlds[i] = 0;
    for (int i = tid; i < 16 * 512; i += 512) {
        int col = i >> 9, t = i & 511;
        xdig[col][t] = (unsigned char)x[(c0 + col) * 512 + t];
    }
    if (tid < 96) onehotpat[tid] = ((tid >> 3) < 8 && (tid & 7) == (tid >> 3)) ? (short)0x3F80 : (short)0;

    // ---- register frags: g (Whg), i (Whi): [rt][kt] ----
    short8 wg0[2][8], wg1[2][8];
    #pragma unroll
    for (int rt = 0; rt < 2; rt++)
        #pragma unroll
        for (int kt = 0; kt < 8; kt++) {
            wg0[rt][kt] = cvt8(Whg + (rw + 16 * rt + l) * 256 + kt * 32 + q * 8);
            wg1[rt][kt] = cvt8(Whi + (rw + 16 * rt + l) * 256 + kt * 32 + q * 8);
        }

    // ---- LDS frags: idx kt = Whf rt0; idx 8+kt = Whf rt1; idx 16 = Who rt0 kt0 ----
    #pragma unroll
    for (int kt = 0; kt < 8; kt++) {
        *(short8*)&wlds[((w * 17 + kt) * 64 + lane) * 8]     = cvt8(Whf + (rw + l) * 256 + kt * 32 + q * 8);
        *(short8*)&wlds[((w * 17 + 8 + kt) * 64 + lane) * 8] = cvt8(Whf + (rw + 16 + l) * 256 + kt * 32 + q * 8);
    }
    *(short8*)&wlds[((w * 17 + 16) * 64 + lane) * 8] = cvt8(Who + (rw + l) * 256 + q * 8);

    // ---- stream copy (15/wave), slot order = consumption order ----
    // slots 0-6 (early, kt0-3): (rt,kt) = (1,0)(0,1)(1,1)(0,2)(1,2)(0,3)(1,3)
    // slots 7-14 (late, kt4-7): (0,4)(1,4)(0,5)(1,5)(0,6)(1,6)(0,7)(1,7)
    short8* wsb = (short8*)(ws + (size_t)bid * WS_STRIDE_SHORTS);
    short8* wsp = wsb + (w * 15) * 64;
    {
        const int srt[15] = {1, 0, 1, 0, 1, 0, 1, 0, 1, 0, 1, 0, 1, 0, 1};
        const int skt[15] = {0, 1, 1, 2, 2, 3, 3, 4, 4, 5, 5, 6, 6, 7, 7};
        #pragma unroll
        for (int s = 0; s < 15; s++)
            wsp[s * 64 + lane] = cvt8(Who + (rw + 16 * srt[s] + l) * 256 + skt[s] * 32 + q * 8);
    }

    // ---- fold frags (kt=8): B k'=0..9 -> Wx@emb[row][d']; k'=10+g' -> gate indicator ----
    short8 oh[4][2];
    #pragma unroll
    for (int g = 0; g < 4; g++)
        #pragma unroll
        for (int rt = 0; rt < 2; rt++) {
            int row = rw + 16 * rt + l;
            short8 v = {0, 0, 0, 0, 0, 0, 0, 0};
            if (q == 0) {
                #pragma unroll
                for (int jj = 0; jj < 8; jj++) {
                    float s = 0.f;
                    #pragma unroll
                    for (int e = 0; e < 6; e++) s += WxT[g][row * 6 + e] * emb[jj * 6 + e];
                    v[jj] = f2b(s);
                }
            } else if (q == 1) {
                #pragma unroll
                for (int jj = 0; jj < 2; jj++) {
                    float s = 0.f;
                    #pragma unroll
                    for (int e = 0; e < 6; e++) s += WxT[g][row * 6 + e] * emb[(8 + jj) * 6 + e];
                    v[jj] = f2b(s);
                }
                v[2 + g] = (short)0x3F80;
            }
            oh[g][rt] = v;
        }

    // A kt=8 q==1 base: j2..5 = bias_g[col l]
    short8 af_base = {0, 0, 0, 0, 0, 0, 0, 0};
    af_base[2] = f2b(bg[c0 + l]);  af_base[3] = f2b(bi[c0 + l]);
    af_base[4] = f2b(bff[c0 + l]); af_base[5] = f2b(bo[c0 + l]);

    float cs[2][4] = {{0.f, 0.f, 0.f, 0.f}, {0.f, 0.f, 0.f, 0.f}};
    const int aoff = l * 264 + q * 8;
    #define LDSF(idx) (*(const short8*)&wlds[((w * 17 + (idx)) * 64 + lane) * 8])

    __syncthreads();   // init LDS + per-wave ws writes drained (barrier implies vmcnt(0))

    // early stream set for t=0
    short8 eA0 = wsp[0 * 64 + lane], eA1 = wsp[1 * 64 + lane], eA2 = wsp[2 * 64 + lane];
    short8 eA3 = wsp[3 * 64 + lane], eA4 = wsp[4 * 64 + lane], eA5 = wsp[5 * 64 + lane];
    short8 eA6 = wsp[6 * 64 + lane];
    short8 lB0, lB1, lB2, lB3, lB4, lB5, lB6, lB7;

    for (int t = 0; t < 512; t++) {
        f32x4 acc[4][2];
        #pragma unroll
        for (int g = 0; g < 4; g++)
            #pragma unroll
            for (int rt = 0; rt < 2; rt++)
                acc[g][rt] = (f32x4){0.f, 0.f, 0.f, 0.f};

        #pragma unroll
        for (int kt = 0; kt < 8; kt++) {
            short8 af = *(const short8*)&hlds[aoff + kt * 32];
            acc[0][0] = MFMA(af, wg0[0][kt], acc[0][0]);
            acc[0][1] = MFMA(af, wg0[1][kt], acc[0][1]);
            acc[1][0] = MFMA(af, wg1[0][kt], acc[1][0]);
            acc[1][1] = MFMA(af, wg1[1][kt], acc[1][1]);
            acc[2][0] = MFMA(af, LDSF(kt), acc[2][0]);
            acc[2][1] = MFMA(af, LDSF(8 + kt), acc[2][1]);
            if (kt == 0) {
                acc[3][0] = MFMA(af, LDSF(16), acc[3][0]);
                acc[3][1] = MFMA(af, eA0, acc[3][1]);
                lB0 = wsp[7 * 64 + lane]; lB1 = wsp[8 * 64 + lane];    // kt4 pair
            } else if (kt == 1) {
                acc[3][0] = MFMA(af, eA1, acc[3][0]);
                acc[3][1] = MFMA(af, eA2, acc[3][1]);
                lB2 = wsp[9 * 64 + lane]; lB3 = wsp[10 * 64 + lane];   // kt5 pair
            } else if (kt == 2) {
                acc[3][0] = MFMA(af, eA3, acc[3][0]);
                acc[3][1] = MFMA(af, eA4, acc[3][1]);
                lB4 = wsp[11 * 64 + lane]; lB5 = wsp[12 * 64 + lane];  // kt6 pair
            } else if (kt == 3) {
                acc[3][0] = MFMA(af, eA5, acc[3][0]);
                acc[3][1] = MFMA(af, eA6, acc[3][1]);
                lB6 = wsp[13 * 64 + lane]; lB7 = wsp[14 * 64 + lane];  // kt7 pair
            } else if (kt == 4) {
                acc[3][0] = MFMA(af, lB0, acc[3][0]);
                acc[3][1] = MFMA(af, lB1, acc[3][1]);
            } else if (kt == 5) {
                acc[3][0] = MFMA(af, lB2, acc[3][0]);
                acc[3][1] = MFMA(af, lB3, acc[3][1]);
            } else if (kt == 6) {
                acc[3][0] = MFMA(af, lB4, acc[3][0]);
                acc[3][1] = MFMA(af, lB5, acc[3][1]);
            } else {
                acc[3][0] = MFMA(af, lB6, acc[3][0]);
                acc[3][1] = MFMA(af, lB7, acc[3][1]);
            }
        }

        // ---- kt=8: folded x-path + bias ----
        {
            int d = xdig[l][t];
            short8 pd = *(const short8*)&onehotpat[d * 8];
            short8 bi8 = af_base;
            bi8[0] = (d == 8) ? (short)0x3F80 : (short)0;
            bi8[1] = (d == 9) ? (short)0x3F80 : (short)0;
            short8 z = {0, 0, 0, 0, 0, 0, 0, 0};
            short8 af8 = (q == 0) ? pd : ((q == 1) ? bi8 : z);
            #pragma unroll
            for (int g = 0; g < 4; g++) {
                acc[g][0] = MFMA(af8, oh[g][0], acc[g][0]);
                acc[g][1] = MFMA(af8, oh[g][1], acc[g][1]);
            }
        }
        __syncthreads();   // all hlds A-reads of h_{t-1} complete

        // prefetch next step's early stream set (distance = whole elementwise phase)
        eA0 = wsp[0 * 64 + lane]; eA1 = wsp[1 * 64 + lane]; eA2 = wsp[2 * 64 + lane];
        eA3 = wsp[3 * 64 + lane]; eA4 = wsp[4 * 64 + lane]; eA5 = wsp[5 * 64 + lane];
        eA6 = wsp[6 * 64 + lane];

        // ---- elementwise: lane owns rows {rw+l, rw+16+l}, cols q*4..q*4+3 ----
        #pragma unroll
        for (int i = 0; i < 4; i++) {
            int col = q * 4 + i;
            #pragma unroll
            for (int rt = 0; rt < 2; rt++) {
                float c = tanh_(acc[0][rt][i]) * sigm(acc[1][rt][i]) + cs[rt][i] * sigm(acc[2][rt][i]);
                cs[rt][i] = c;
                float hh = tanh_(c) * sigm(acc[3][rt][i]);
                hlds[col * 264 + rw + 16 * rt + l] = f2b(hh);
            }
        }
        __syncthreads();   // h_t fully written
    }

    // ---- projection ----
    if (tid < 160) {
        int col = tid / 10, cls = tid - col * 10;
        const short* hcol = &hlds[col * 264];
        const float* wrow = Wp + cls * 256;
        float s = 0.f;
        #pragma unroll 8
        for (int k = 0; k < 256; k++) s += b2f(hcol[k]) * wrow[k];
        out[(c0 + col) * 10 + cls] = s + bp[cls];
    }
    #undef LDSF
}

extern "C" void kernel_launch(void* const* d_in, const int* in_sizes, int n_in,
                              void* d_out, int out_size, void* d_ws, size_t ws_size,
                              hipStream_t stream) {
    const int*   x   = (const int*)d_in[0];
    const float* emb = (const float*)d_in[1];
    const float* Wxg = (const float*)d_in[2];
    const float* Whg = (const float*)d_in[3];
    const float* bg  = (const float*)d_in[4];
    const float* Wxi = (const float*)d_in[5];
    const float* Whi = (const float*)d_in[6];
    const float* bi  = (const float*)d_in[7];
    const float* Wxf = (const float*)d_in[8];
    const float* Whf = (const float*)d_in[9];
    const float* bff = (const float*)d_in[10];
    const float* Wxo = (const float*)d_in[11];
    const float* Who = (const float*)d_in[12];
    const float* bo  = (const float*)d_in[13];
    const float* Wp  = (const float*)d_in[14];
    const float* bp  = (const float*)d_in[15];

    hipLaunchKernelGGL(lstm_block, dim3(16), dim3(512), 0, stream,
                       x, emb, Wxg, Whg, bg, Wxi, Whi, bi, Wxf, Whf, bff,
                       Wxo, Who, bo, Wp, bp,
                       (float*)d_out, (short*)d_ws);
}

// Round 6
// 1117.832 us; speedup vs baseline: 5.7903x; 1.6701x over previous
//
#include <hip/hip_runtime.h>
#include <hip/hip_bf16.h>

// LSTM B=256 T=512 H=256 E=6 V=10 C=10. fp32 in/out.
// 16 blocks x 512 threads (8 waves, 2/SIMD). Block owns 16 batch cols; wave w
// owns hidden rows 32w..32w+31 for all 4 gates.
// INT8 path: weights quantized per-row (s_r = max|row|) into i8 MFMA A-frags,
// 100% register-resident (128 regs/wave); h quantized with fixed scale 127
// (h in (-1,1)), lives in LDS as [col][k] i8. mfma_i32_16x16x64_i8: 4 K-tiles,
// 32 MFMAs/wave/step, i32 accumulation exact. x-path via LDS table
// tbl[row][digit] with gate input scales (-2.8854 tanh / -1.4427 sigm) folded
// into table + dequant scale. A=W (m=row), B=h (n=col), D rows = quad*4+i ->
// h-store is one packed b32 per rt. Final h kept in bf16 (hfin) for projection.

typedef __attribute__((ext_vector_type(4))) int   int4v;
typedef __attribute__((ext_vector_type(8))) short short8;
typedef __attribute__((ext_vector_type(4))) short short4v;
typedef __attribute__((ext_vector_type(4))) float float4v;

#define MFMA_I8(a, b, c) __builtin_amdgcn_mfma_i32_16x16x64_i8(a, b, c, 0, 0, 0)

#define K_TANH (-2.8853900817779268f)   // exp2(K_TANH*x) = e^(-2x)
#define K_SIG  (-1.4426950408889634f)   // exp2(K_SIG*x)  = e^(-x)

__device__ __forceinline__ float b2f(short s) {
    union { unsigned int u; float f; } v; v.u = ((unsigned int)(unsigned short)s) << 16; return v.f;
}
__device__ __forceinline__ short f2b(float f) {
    __hip_bfloat16 b = __float2bfloat16(f); return *(short*)&b;
}
__device__ __forceinline__ float fexp2(float x) {
#if __has_builtin(__builtin_amdgcn_exp2f)
    return __builtin_amdgcn_exp2f(x);
#else
    return __expf(x * 0.6931471805599453f);
#endif
}
__device__ __forceinline__ float frcp(float x) { return __builtin_amdgcn_rcpf(x); }

__global__ __attribute__((amdgpu_flat_work_group_size(512, 512), amdgpu_waves_per_eu(2, 2)))
void lstm_i8(
    const int* __restrict__ x,
    const float* __restrict__ emb,
    const float* __restrict__ Wxg, const float* __restrict__ Whg, const float* __restrict__ bg,
    const float* __restrict__ Wxi, const float* __restrict__ Whi, const float* __restrict__ bi,
    const float* __restrict__ Wxf, const float* __restrict__ Whf, const float* __restrict__ bff,
    const float* __restrict__ Wxo, const float* __restrict__ Who, const float* __restrict__ bo,
    const float* __restrict__ Wp, const float* __restrict__ bp,
    float* __restrict__ out)
{
    const int tid = threadIdx.x, bid = blockIdx.x;
    const int c0 = bid * 16;
    const int w = tid >> 6, lane = tid & 63;
    const int l = lane & 15, q = lane >> 4;
    const int rw = 32 * w;

    __shared__ __align__(16) unsigned int hlds_u[16 * 272 / 4];  // h i8 [col][k], stride 272
    __shared__ __align__(16) short hfin[16 * 264];               // final h bf16 [col][k]
    __shared__ unsigned char xdig2[512 * 16];                    // [t][col]
    __shared__ __align__(16) short tblL[16 * 720];               // [w2rt][d][q][g*4+i] bf16, scaled
    __shared__ float scaleL[4 * 256];                            // per-gate per-row max|W|

    const float* WxT[4] = {Wxg, Wxi, Wxf, Wxo};
    const float* WhT[4] = {Whg, Whi, Whf, Who};

    // ---- init: zero h, stage digits ----
    for (int i = tid; i < 16 * 272 / 4; i += 512) hlds_u[i] = 0u;
    for (int i = tid; i < 8192; i += 512)
        xdig2[i] = (unsigned char)x[(c0 + (i & 15)) * 512 + (i >> 4)];

    // ---- x-path table, gate-scale folded: tbl = kg * (Wx@emb)[row][d] ----
    for (int i = tid; i < 10240; i += 512) {
        int gi = i & 15, g = gi >> 2, io = gi & 3;
        int qq = (i >> 4) & 3;
        int d  = (i >> 6) % 10;
        int rtw = i / 640;                                   // w*2+rt
        int row = (rtw >> 1) * 32 + (rtw & 1) * 16 + qq * 4 + io;
        float s = 0.f;
        #pragma unroll
        for (int e = 0; e < 6; e++) s += WxT[g][row * 6 + e] * emb[d * 6 + e];
        tblL[rtw * 720 + d * 72 + qq * 16 + gi] = f2b(s * (g == 0 ? K_TANH : K_SIG));
    }

    // ---- weight quantization: per-row scale, i8 A-frags in registers ----
    // A[m=lane&15 -> row rw+16rt+l][k = 64kt+16q+j], 16 i8 per lane per kt
    int4v wa[4][2][4];
    #pragma unroll
    for (int g = 0; g < 4; g++)
        #pragma unroll
        for (int rt = 0; rt < 2; rt++) {
            const float* Wr = WhT[g] + (rw + 16 * rt + l) * 256 + q * 16;
            float mx = 0.f;
            #pragma unroll
            for (int kt = 0; kt < 4; kt++)
                #pragma unroll
                for (int c4 = 0; c4 < 4; c4++) {
                    float4v v = *(const float4v*)(Wr + kt * 64 + c4 * 4);
                    #pragma unroll
                    for (int j = 0; j < 4; j++) mx = fmaxf(mx, fabsf(v[j]));
                }
            mx = fmaxf(mx, __shfl_xor(mx, 16));
            mx = fmaxf(mx, __shfl_xor(mx, 32));
            mx = fmaxf(mx, 1e-20f);
            if (q == 0) scaleL[g * 256 + rw + 16 * rt + l] = mx;
            float qs = 127.f / mx;
            #pragma unroll
            for (int kt = 0; kt < 4; kt++) {
                int4v f;
                #pragma unroll
                for (int dw = 0; dw < 4; dw++) {
                    float4v v = *(const float4v*)(Wr + kt * 64 + dw * 4);
                    int word = 0;
                    #pragma unroll
                    for (int byt = 0; byt < 4; byt++) {
                        int z = (int)rintf(v[byt] * qs);
                        word |= (z & 255) << (8 * byt);
                    }
                    f[dw] = word;
                }
                wa[g][rt][kt] = f;
            }
        }

    __syncthreads();   // scaleL/tblL/xdig2/hlds visible

    // ---- loop-invariant dequant scales (rows rw+16rt+4q+i) and biases (col l) ----
    float dscl[4][8];
    #pragma unroll
    for (int g = 0; g < 4; g++) {
        float kk = (g == 0 ? K_TANH : K_SIG) * (1.f / 16129.f);   // 127^2
        #pragma unroll
        for (int rt = 0; rt < 2; rt++)
            #pragma unroll
            for (int i = 0; i < 4; i++)
                dscl[g][rt * 4 + i] = scaleL[g * 256 + rw + 16 * rt + 4 * q + i] * kk;
    }
    float bSc[4];
    bSc[0] = bg[c0 + l] * K_TANH; bSc[1] = bi[c0 + l] * K_SIG;
    bSc[2] = bff[c0 + l] * K_SIG; bSc[3] = bo[c0 + l] * K_SIG;

    float cs[2][4] = {{0.f, 0.f, 0.f, 0.f}, {0.f, 0.f, 0.f, 0.f}};
    const char* hbase = (const char*)hlds_u + l * 272 + q * 16;

    for (int t = 0; t < 512; t++) {
        int4v acc[4][2];
        #pragma unroll
        for (int g = 0; g < 4; g++)
            #pragma unroll
            for (int rt = 0; rt < 2; rt++)
                acc[g][rt] = (int4v){0, 0, 0, 0};

        int dg = xdig2[t * 16 + l];
        const short* tp0 = &tblL[(w * 2 + 0) * 720 + dg * 72 + q * 16];
        const short* tp1 = &tblL[(w * 2 + 1) * 720 + dg * 72 + q * 16];
        short8 tv0a = *(const short8*)tp0, tv0b = *(const short8*)(tp0 + 8);
        short8 tv1a = *(const short8*)tp1, tv1b = *(const short8*)(tp1 + 8);

        #pragma unroll
        for (int kt = 0; kt < 4; kt++) {
            int4v hf = *(const int4v*)(hbase + kt * 64);   // B[k=64kt+16q+j][n=col l]
            #pragma unroll
            for (int g = 0; g < 4; g++) {
                acc[g][0] = MFMA_I8(wa[g][0][kt], hf, acc[g][0]);
                acc[g][1] = MFMA_I8(wa[g][1][kt], hf, acc[g][1]);
            }
        }
        __syncthreads();   // all h_{t-1} reads complete

        // ---- elementwise: thread owns rows rw+16rt+4q+i (i=0..3), col l ----
        #pragma unroll
        for (int rt = 0; rt < 2; rt++) {
            short8 tA = rt ? tv1a : tv0a;   // g0 (i0..3), g1 (i0..3)
            short8 tB = rt ? tv1b : tv0b;   // g2, g3
            int word = 0;
            float hh4[4];
            #pragma unroll
            for (int i = 0; i < 4; i++) {
                float pg = fmaf((float)acc[0][rt][i], dscl[0][rt * 4 + i], b2f(tA[i])     + bSc[0]);
                float pi = fmaf((float)acc[1][rt][i], dscl[1][rt * 4 + i], b2f(tA[4 + i]) + bSc[1]);
                float pf = fmaf((float)acc[2][rt][i], dscl[2][rt * 4 + i], b2f(tB[i])     + bSc[2]);
                float po = fmaf((float)acc[3][rt][i], dscl[3][rt * 4 + i], b2f(tB[4 + i]) + bSc[3]);
                float gg = fmaf(2.f, frcp(1.f + fexp2(pg)), -1.f);   // tanh
                float ii = frcp(1.f + fexp2(pi));
                float ff = frcp(1.f + fexp2(pf));
                float oo = frcp(1.f + fexp2(po));
                float c  = fmaf(gg, ii, cs[rt][i] * ff);
                cs[rt][i] = c;
                float th = fmaf(2.f, frcp(1.f + fexp2(K_TANH * c)), -1.f);
                float hh = th * oo;
                hh4[i] = hh;
                int hq = (int)rintf(hh * 127.f);
                word |= (hq & 255) << (8 * i);
            }
            *(int*)((char*)hlds_u + l * 272 + rw + 16 * rt + 4 * q) = word;
            if (t == 511) {
                short4v hw;
                hw[0] = f2b(hh4[0]); hw[1] = f2b(hh4[1]);
                hw[2] = f2b(hh4[2]); hw[3] = f2b(hh4[3]);
                *(short4v*)&hfin[l * 264 + rw + 16 * rt + 4 * q] = hw;
            }
        }
        __syncthreads();   // h_t fully written
    }

    // ---- projection: out[c0+col][cls] = Wp[cls] . h_final + bp[cls] ----
    if (tid < 160) {
        int col = tid / 10, cls = tid - col * 10;
        const short* hcol = &hfin[col * 264];
        const float* wrow = Wp + cls * 256;
        float s = 0.f;
        #pragma unroll 8
        for (int k = 0; k < 256; k++) s += b2f(hcol[k]) * wrow[k];
        out[(c0 + col) * 10 + cls] = s + bp[cls];
    }
}

extern "C" void kernel_launch(void* const* d_in, const int* in_sizes, int n_in,
                              void* d_out, int out_size, void* d_ws, size_t ws_size,
                              hipStream_t stream) {
    const int*   x   = (const int*)d_in[0];
    const float* emb = (const float*)d_in[1];
    const float* Wxg = (const float*)d_in[2];
    const float* Whg = (const float*)d_in[3];
    const float* bg  = (const float*)d_in[4];
    const float* Wxi = (const float*)d_in[5];
    const float* Whi = (const float*)d_in[6];
    const float* bi  = (const float*)d_in[7];
    const float* Wxf = (const float*)d_in[8];
    const float* Whf = (const float*)d_in[9];
    const float* bff = (const float*)d_in[10];
    const float* Wxo = (const float*)d_in[11];
    const float* Who = (const float*)d_in[12];
    const float* bo  = (const float*)d_in[13];
    const float* Wp  = (const float*)d_in[14];
    const float* bp  = (const float*)d_in[15];

    hipLaunchKernelGGL(lstm_i8, dim3(16), dim3(512), 0, stream,
                       x, emb, Wxg, Whg, bg, Wxi, Whi, bi, Wxf, Whf, bff,
                       Wxo, Who, bo, Wp, bp, (float*)d_out);
}

// Round 7
// 1100.048 us; speedup vs baseline: 5.8839x; 1.0162x over previous
//
#include <hip/hip_runtime.h>
#include <hip/hip_bf16.h>

// LSTM B=256 T=512 H=256 E=6 V=10 C=10. fp32 in/out.
// 16 blocks x 512 threads (8 waves, 2/SIMD). Block owns 16 batch cols; wave w
// owns hidden rows 32w..32w+31 for all 4 gates.
// INT8 path: weights per-row quantized into register-resident i8 MFMA A-frags
// (mfma_i32_16x16x64_i8, exact i32 accum); h quantized at 127 in LDS.
// ROUND 7: h double-buffered in LDS -> ONE barrier per step; waves overlap
// MFMA phase (matrix pipe) with elementwise phase (VALU/transcendental pipe).

typedef __attribute__((ext_vector_type(4))) int   int4v;
typedef __attribute__((ext_vector_type(8))) short short8;
typedef __attribute__((ext_vector_type(4))) short short4v;
typedef __attribute__((ext_vector_type(4))) float float4v;

#define MFMA_I8(a, b, c) __builtin_amdgcn_mfma_i32_16x16x64_i8(a, b, c, 0, 0, 0)

#define K_TANH (-2.8853900817779268f)   // exp2(K_TANH*x) = e^(-2x)
#define K_SIG  (-1.4426950408889634f)   // exp2(K_SIG*x)  = e^(-x)

__device__ __forceinline__ float b2f(short s) {
    union { unsigned int u; float f; } v; v.u = ((unsigned int)(unsigned short)s) << 16; return v.f;
}
__device__ __forceinline__ short f2b(float f) {
    __hip_bfloat16 b = __float2bfloat16(f); return *(short*)&b;
}
__device__ __forceinline__ float fexp2(float x) {
#if __has_builtin(__builtin_amdgcn_exp2f)
    return __builtin_amdgcn_exp2f(x);
#else
    return __expf(x * 0.6931471805599453f);
#endif
}
__device__ __forceinline__ float frcp(float x) { return __builtin_amdgcn_rcpf(x); }

__global__ __attribute__((amdgpu_flat_work_group_size(512, 512), amdgpu_waves_per_eu(2, 2)))
void lstm_i8(
    const int* __restrict__ x,
    const float* __restrict__ emb,
    const float* __restrict__ Wxg, const float* __restrict__ Whg, const float* __restrict__ bg,
    const float* __restrict__ Wxi, const float* __restrict__ Whi, const float* __restrict__ bi,
    const float* __restrict__ Wxf, const float* __restrict__ Whf, const float* __restrict__ bff,
    const float* __restrict__ Wxo, const float* __restrict__ Who, const float* __restrict__ bo,
    const float* __restrict__ Wp, const float* __restrict__ bp,
    float* __restrict__ out)
{
    const int tid = threadIdx.x, bid = blockIdx.x;
    const int c0 = bid * 16;
    const int w = tid >> 6, lane = tid & 63;
    const int l = lane & 15, q = lane >> 4;
    const int rw = 32 * w;

    __shared__ __align__(16) unsigned int hbuf[2][16 * 272 / 4];  // h i8 [parity][col][k]
    __shared__ __align__(16) short hfin[16 * 264];                // final h bf16 [col][k]
    __shared__ unsigned char xdig2[512 * 16];                     // [t][col]
    __shared__ __align__(16) short tblL[16 * 720];                // [w2rt][d][q][g*4+i] bf16
    __shared__ float scaleL[4 * 256];                             // per-gate per-row max|W|

    const float* WxT[4] = {Wxg, Wxi, Wxf, Wxo};
    const float* WhT[4] = {Whg, Whi, Whf, Who};

    // ---- init: zero h buf0, stage digits ----
    for (int i = tid; i < 16 * 272 / 4; i += 512) hbuf[0][i] = 0u;
    for (int i = tid; i < 8192; i += 512)
        xdig2[i] = (unsigned char)x[(c0 + (i & 15)) * 512 + (i >> 4)];

    // ---- x-path table, gate-scale folded: tbl = kg * (Wx@emb)[row][d] ----
    for (int i = tid; i < 10240; i += 512) {
        int gi = i & 15, g = gi >> 2, io = gi & 3;
        int qq = (i >> 4) & 3;
        int d  = (i >> 6) % 10;
        int rtw = i / 640;                                   // w*2+rt
        int row = (rtw >> 1) * 32 + (rtw & 1) * 16 + qq * 4 + io;
        float s = 0.f;
        #pragma unroll
        for (int e = 0; e < 6; e++) s += WxT[g][row * 6 + e] * emb[d * 6 + e];
        tblL[rtw * 720 + d * 72 + qq * 16 + gi] = f2b(s * (g == 0 ? K_TANH : K_SIG));
    }

    // ---- weight quantization: per-row scale, i8 A-frags in registers ----
    // A[m=lane&15 -> row rw+16rt+l][k = 64kt+16q+j], 16 i8 per lane per kt
    int4v wa[4][2][4];
    #pragma unroll
    for (int g = 0; g < 4; g++)
        #pragma unroll
        for (int rt = 0; rt < 2; rt++) {
            const float* Wr = WhT[g] + (rw + 16 * rt + l) * 256 + q * 16;
            float mx = 0.f;
            #pragma unroll
            for (int kt = 0; kt < 4; kt++)
                #pragma unroll
                for (int c4 = 0; c4 < 4; c4++) {
                    float4v v = *(const float4v*)(Wr + kt * 64 + c4 * 4);
                    #pragma unroll
                    for (int j = 0; j < 4; j++) mx = fmaxf(mx, fabsf(v[j]));
                }
            mx = fmaxf(mx, __shfl_xor(mx, 16));
            mx = fmaxf(mx, __shfl_xor(mx, 32));
            mx = fmaxf(mx, 1e-20f);
            if (q == 0) scaleL[g * 256 + rw + 16 * rt + l] = mx;
            float qs = 127.f / mx;
            #pragma unroll
            for (int kt = 0; kt < 4; kt++) {
                int4v f;
                #pragma unroll
                for (int dw = 0; dw < 4; dw++) {
                    float4v v = *(const float4v*)(Wr + kt * 64 + dw * 4);
                    int word = 0;
                    #pragma unroll
                    for (int byt = 0; byt < 4; byt++) {
                        int z = (int)rintf(v[byt] * qs);
                        word |= (z & 255) << (8 * byt);
                    }
                    f[dw] = word;
                }
                wa[g][rt][kt] = f;
            }
        }

    __syncthreads();   // scaleL/tblL/xdig2/hbuf[0] visible

    // ---- loop-invariant dequant scales (rows rw+16rt+4q+i) and biases (col l) ----
    float dscl[4][8];
    #pragma unroll
    for (int g = 0; g < 4; g++) {
        float kk = (g == 0 ? K_TANH : K_SIG) * (1.f / 16129.f);   // 127^2
        #pragma unroll
        for (int rt = 0; rt < 2; rt++)
            #pragma unroll
            for (int i = 0; i < 4; i++)
                dscl[g][rt * 4 + i] = scaleL[g * 256 + rw + 16 * rt + 4 * q + i] * kk;
    }
    float bSc[4];
    bSc[0] = bg[c0 + l] * K_TANH; bSc[1] = bi[c0 + l] * K_SIG;
    bSc[2] = bff[c0 + l] * K_SIG; bSc[3] = bo[c0 + l] * K_SIG;

    float cs[2][4] = {{0.f, 0.f, 0.f, 0.f}, {0.f, 0.f, 0.f, 0.f}};

    for (int t = 0; t < 512; t++) {
        const int p = t & 1;
        const char* hbase = (const char*)hbuf[p] + l * 272 + q * 16;
        char*       hdst  = (char*)hbuf[1 - p]  + l * 272 + rw + 4 * q;

        int4v acc[4][2];
        #pragma unroll
        for (int g = 0; g < 4; g++)
            #pragma unroll
            for (int rt = 0; rt < 2; rt++)
                acc[g][rt] = (int4v){0, 0, 0, 0};

        int dg = xdig2[t * 16 + l];
        const short* tp0 = &tblL[(w * 2 + 0) * 720 + dg * 72 + q * 16];
        const short* tp1 = &tblL[(w * 2 + 1) * 720 + dg * 72 + q * 16];
        short8 tv0a = *(const short8*)tp0, tv0b = *(const short8*)(tp0 + 8);
        short8 tv1a = *(const short8*)tp1, tv1b = *(const short8*)(tp1 + 8);

        #pragma unroll
        for (int kt = 0; kt < 4; kt++) {
            int4v hf = *(const int4v*)(hbase + kt * 64);   // B[k=64kt+16q+j][n=col l]
            #pragma unroll
            for (int g = 0; g < 4; g++) {
                acc[g][0] = MFMA_I8(wa[g][0][kt], hf, acc[g][0]);
                acc[g][1] = MFMA_I8(wa[g][1][kt], hf, acc[g][1]);
            }
        }
        // no barrier here: writes go to the other buffer (double-buffered)

        // ---- elementwise: thread owns rows rw+16rt+4q+i (i=0..3), col l ----
        #pragma unroll
        for (int rt = 0; rt < 2; rt++) {
            short8 tA = rt ? tv1a : tv0a;   // g0 (i0..3), g1 (i0..3)
            short8 tB = rt ? tv1b : tv0b;   // g2, g3
            int word = 0;
            float hh4[4];
            #pragma unroll
            for (int i = 0; i < 4; i++) {
                float pg = fmaf((float)acc[0][rt][i], dscl[0][rt * 4 + i], b2f(tA[i])     + bSc[0]);
                float pi = fmaf((float)acc[1][rt][i], dscl[1][rt * 4 + i], b2f(tA[4 + i]) + bSc[1]);
                float pf = fmaf((float)acc[2][rt][i], dscl[2][rt * 4 + i], b2f(tB[i])     + bSc[2]);
                float po = fmaf((float)acc[3][rt][i], dscl[3][rt * 4 + i], b2f(tB[4 + i]) + bSc[3]);
                float gg = fmaf(2.f, frcp(1.f + fexp2(pg)), -1.f);   // tanh
                float ii = frcp(1.f + fexp2(pi));
                float ff = frcp(1.f + fexp2(pf));
                float oo = frcp(1.f + fexp2(po));
                float c  = fmaf(gg, ii, cs[rt][i] * ff);
                cs[rt][i] = c;
                float th = fmaf(2.f, frcp(1.f + fexp2(K_TANH * c)), -1.f);
                float hh = th * oo;
                hh4[i] = hh;
                int hq = (int)rintf(hh * 127.f);
                word |= (hq & 255) << (8 * i);
            }
            *(int*)(hdst + 16 * rt) = word;
            if (t == 511) {
                short4v hw;
                hw[0] = f2b(hh4[0]); hw[1] = f2b(hh4[1]);
                hw[2] = f2b(hh4[2]); hw[3] = f2b(hh4[3]);
                *(short4v*)&hfin[l * 264 + rw + 16 * rt + 4 * q] = hw;
            }
        }
        __syncthreads();   // h_t (other buffer) fully written; h_{t-1} reads all done
    }

    // ---- projection: out[c0+col][cls] = Wp[cls] . h_final + bp[cls] ----
    if (tid < 160) {
        int col = tid / 10, cls = tid - col * 10;
        const short* hcol = &hfin[col * 264];
        const float* wrow = Wp + cls * 256;
        float s = 0.f;
        #pragma unroll 8
        for (int k = 0; k < 256; k++) s += b2f(hcol[k]) * wrow[k];
        out[(c0 + col) * 10 + cls] = s + bp[cls];
    }
}

extern "C" void kernel_launch(void* const* d_in, const int* in_sizes, int n_in,
                              void* d_out, int out_size, void* d_ws, size_t ws_size,
                              hipStream_t stream) {
    const int*   x   = (const int*)d_in[0];
    const float* emb = (const float*)d_in[1];
    const float* Wxg = (const float*)d_in[2];
    const float* Whg = (const float*)d_in[3];
    const float* bg  = (const float*)d_in[4];
    const float* Wxi = (const float*)d_in[5];
    const float* Whi = (const float*)d_in[6];
    const float* bi  = (const float*)d_in[7];
    const float* Wxf = (const float*)d_in[8];
    const float* Whf = (const float*)d_in[9];
    const float* bff = (const float*)d_in[10];
    const float* Wxo = (const float*)d_in[11];
    const float* Who = (const float*)d_in[12];
    const float* bo  = (const float*)d_in[13];
    const float* Wp  = (const float*)d_in[14];
    const float* bp  = (const float*)d_in[15];

    hipLaunchKernelGGL(lstm_i8, dim3(16), dim3(512), 0, stream,
                       x, emb, Wxg, Whg, bg, Wxi, Whi, bi, Wxf, Whf, bff,
                       Wxo, Who, bo, Wp, bp, (float*)d_out);
}